// Round 12
// baseline (231.552 us; speedup 1.0000x reference)
//
#include <hip/hip_runtime.h>
#include <hip/hip_bf16.h>
#include <math.h>

#define B_ 4
#define S_ 1024
#define D_ 1024
#define NH_ 16
#define HD_ 64
#define I_ 4096
#define M_ (B_*S_)

typedef __bf16 bf16_8 __attribute__((ext_vector_type(8)));
typedef float f32x4 __attribute__((ext_vector_type(4)));
typedef unsigned int u32x2 __attribute__((ext_vector_type(2)));
typedef unsigned short u16;

struct PB { u16* p[4]; };
struct Prep {
    const float* s[6]; u16* d[6]; int K[6]; int N[6];
    const float4* cin; ushort4* cout;
};

__device__ __forceinline__ u16 f2b(float x) {
    __hip_bfloat16 h = __float2bfloat16(x);
    return *reinterpret_cast<u16*>(&h);
}
__device__ __forceinline__ float b2f(u16 x) {
    return __uint_as_float(((unsigned)x) << 16);
}

__device__ __forceinline__ void gload16(const void* g, void* l) {
    __builtin_amdgcn_global_load_lds(
        (const __attribute__((address_space(1))) void*)g,
        (__attribute__((address_space(3))) void*)l, 16, 0, 0);
}

// exact-GELU via A&S 7.1.26 erf poly (max abs err 1.5e-7, no systematic bias)
__device__ __forceinline__ float gelu_f(float v) {
    const float z  = v * 0.70710678118654752f;
    const float az = fabsf(z);
    const float t  = __fdividef(1.0f, 1.0f + 0.3275911f * az);
    const float poly = t * (0.254829592f + t * (-0.284496736f +
                       t * (1.421413741f + t * (-1.453152027f + t * 1.061405429f))));
    const float erfa = 1.0f - poly * __expf(-z * z);
    const float erfv = copysignf(erfa, z);
    return 0.5f * v * (1.0f + erfv);
}

// ---------------------------------------------------------------------------
// Fused prep: z=0..5 -> W[K][N] fp32 -> Wt[N][K] bf16 transposes;
// z=6 -> h fp32 -> bf16 convert. Grid (128, 32, 7); surplus tiles early-exit.
// ---------------------------------------------------------------------------
__global__ __launch_bounds__(256) void prep_all(Prep p)
{
    const int tid = threadIdx.x;
    const int z = blockIdx.z;
    const int tile = blockIdx.y * 128 + blockIdx.x;

    if (z == 6) {
        const int i = tile * 256 + tid;
        float4 v = p.cin[i];
        ushort4 o;
        o.x = f2b(v.x); o.y = f2b(v.y); o.z = f2b(v.z); o.w = f2b(v.w);
        p.cout[i] = o;
        return;
    }

    const int K = p.K[z], N = p.N[z];
    const int ntile = N >> 5;
    if (tile >= (K >> 5) * ntile) return;
    const int k0 = (tile / ntile) * 32, n0 = (tile % ntile) * 32;
    const float* in = p.s[z];
    u16* out = p.d[z];

    __shared__ float t[32][33];
#pragma unroll
    for (int i = 0; i < 4; ++i) {
        int idx = i * 256 + tid;
        int r = idx >> 5, c = idx & 31;
        t[r][c] = in[(size_t)(k0 + r) * N + n0 + c];
    }
    __syncthreads();
    const int rr = tid >> 3, cc0 = (tid & 7) * 4;
    ushort4 o;
    o.x = f2b(t[cc0 + 0][rr]);
    o.y = f2b(t[cc0 + 1][rr]);
    o.z = f2b(t[cc0 + 2][rr]);
    o.w = f2b(t[cc0 + 3][rr]);
    *(ushort4*)(out + (size_t)(n0 + rr) * K + k0 + cc0) = o;
}

// ---------------------------------------------------------------------------
// 256x256 8-phase bf16 MFMA GEMM (runtime strides).
// MODE 0: +bias(QKV-select) -> bf16.  MODE 1: +bias+erf-GELU -> bf16.
// MODE 2: split-K bf16 partial (blockIdx.z selects chunk+partial buffer).
// ---------------------------------------------------------------------------
#define NT_ 16

template<int MODE>
__global__ __launch_bounds__(512, 2) void gemm256(
    const u16* __restrict__ A, const u16* __restrict__ Bt,
    const float* __restrict__ b0, const float* __restrict__ b1,
    const float* __restrict__ b2,
    u16* __restrict__ outB, PB parts, int N, int sA, int sB)
{
    __shared__ __align__(16) char sm[131072];

    const int tid  = threadIdx.x;
    const int lane = tid & 63, wid = tid >> 6;
    const int l15  = lane & 15, lg = lane >> 4;
    const int gm   = wid >> 2, gn = wid & 3;
    const int bm   = blockIdx.y * 256, bn = blockIdx.x * 256;
    const int koff = (MODE == 2) ? blockIdx.z * 1024 : 0;

    const int srow = (wid << 3) + (lane >> 3);
    const int skb  = ((lane & 7) << 4) ^ (((lane >> 3) & 7) << 4);
    const int scol = skb >> 1;
    const int xm   = (l15 & 7) << 4;

    f32x4 acc[8][4];
#pragma unroll
    for (int m = 0; m < 8; ++m)
#pragma unroll
        for (int j = 0; j < 4; ++j) {
            acc[m][j][0] = 0.f; acc[m][j][1] = 0.f;
            acc[m][j][2] = 0.f; acc[m][j][3] = 0.f;
        }

    auto stageA = [&](int v, int h) {
        const u16* src = A + (size_t)(bm + h * 128 + srow) * sA + koff + v * 64 + scol;
        char* dst = sm + ((v & 1) * 65536 + h * 16384 + wid * 1024);
        gload16(src, dst);
        gload16(src + (size_t)64 * sA, dst + 8192);
    };
    auto stageB = [&](int v, int h) {
        const u16* src = Bt + (size_t)(bn + h * 128 + srow) * sB + koff + v * 64 + scol;
        char* dst = sm + ((v & 1) * 65536 + 32768 + h * 16384 + wid * 1024);
        gload16(src, dst);
        gload16(src + (size_t)64 * sB, dst + 8192);
    };

    bf16_8 a[8], bb[2];
    auto loadA = [&](int vb, int s) {
        const char* base = sm + (vb * 65536 + gm * 16384);
#pragma unroll
        for (int m = 0; m < 8; ++m)
            a[m] = *(const bf16_8*)(base + (m * 16 + l15) * 128 +
                                    ((s * 64 + lg * 16) ^ xm));
    };
    auto loadB = [&](int vb, int s, int np) {
        const char* base = sm + (vb * 65536 + 32768 + (gn >> 1) * 16384);
#pragma unroll
        for (int j = 0; j < 2; ++j)
            bb[j] = *(const bf16_8*)(base + ((gn & 1) * 64 + (np * 2 + j) * 16 + l15) * 128 +
                                     ((s * 64 + lg * 16) ^ xm));
    };
    auto mfma16 = [&](int np) {
#pragma unroll
        for (int m = 0; m < 8; ++m)
#pragma unroll
            for (int j = 0; j < 2; ++j)
                acc[m][np * 2 + j] = __builtin_amdgcn_mfma_f32_16x16x32_bf16(
                    a[m], bb[j], acc[m][np * 2 + j], 0, 0, 0);
    };

    // prologue
    stageA(0, 0); stageA(0, 1);
    stageB(0, 0); stageB(0, 1);
    stageA(1, 0); stageA(1, 1);
    asm volatile("s_waitcnt vmcnt(4)" ::: "memory");
    __builtin_amdgcn_sched_barrier(0);
    __builtin_amdgcn_s_barrier();

    for (int v = 0; v < NT_ - 2; ++v) {
        const int vb = v & 1;
        loadA(vb, 0); loadB(vb, 0, 0);
        stageB(v + 1, 0); stageB(v + 1, 1);
        __builtin_amdgcn_s_barrier();
        asm volatile("s_waitcnt lgkmcnt(0)" ::: "memory");
        __builtin_amdgcn_s_setprio(1); mfma16(0); __builtin_amdgcn_s_setprio(0);
        __builtin_amdgcn_s_barrier();
        loadB(vb, 0, 1);
        __builtin_amdgcn_s_barrier();
        asm volatile("s_waitcnt lgkmcnt(0)" ::: "memory");
        __builtin_amdgcn_s_setprio(1); mfma16(1); __builtin_amdgcn_s_setprio(0);
        __builtin_amdgcn_s_barrier();
        loadA(vb, 1); loadB(vb, 1, 0);
        __builtin_amdgcn_s_barrier();
        asm volatile("s_waitcnt lgkmcnt(0)" ::: "memory");
        __builtin_amdgcn_s_setprio(1); mfma16(0); __builtin_amdgcn_s_setprio(0);
        __builtin_amdgcn_s_barrier();
        loadB(vb, 1, 1);
        stageA(v + 2, 0); stageA(v + 2, 1);
        __builtin_amdgcn_s_barrier();
        asm volatile("s_waitcnt lgkmcnt(0)" ::: "memory");
        __builtin_amdgcn_s_setprio(1); mfma16(1); __builtin_amdgcn_s_setprio(0);
        asm volatile("s_waitcnt vmcnt(4)" ::: "memory");
        __builtin_amdgcn_sched_barrier(0);
        __builtin_amdgcn_s_barrier();
    }
    {
        const int vb = (NT_ - 2) & 1;
        loadA(vb, 0); loadB(vb, 0, 0);
        stageB(NT_ - 1, 0); stageB(NT_ - 1, 1);
        __builtin_amdgcn_s_barrier();
        asm volatile("s_waitcnt lgkmcnt(0)" ::: "memory");
        __builtin_amdgcn_s_setprio(1); mfma16(0); __builtin_amdgcn_s_setprio(0);
        __builtin_amdgcn_s_barrier();
        loadB(vb, 0, 1);
        __builtin_amdgcn_s_barrier();
        asm volatile("s_waitcnt lgkmcnt(0)" ::: "memory");
        __builtin_amdgcn_s_setprio(1); mfma16(1); __builtin_amdgcn_s_setprio(0);
        __builtin_amdgcn_s_barrier();
        loadA(vb, 1); loadB(vb, 1, 0);
        __builtin_amdgcn_s_barrier();
        asm volatile("s_waitcnt lgkmcnt(0)" ::: "memory");
        __builtin_amdgcn_s_setprio(1); mfma16(0); __builtin_amdgcn_s_setprio(0);
        __builtin_amdgcn_s_barrier();
        loadB(vb, 1, 1);
        __builtin_amdgcn_s_barrier();
        asm volatile("s_waitcnt lgkmcnt(0)" ::: "memory");
        __builtin_amdgcn_s_setprio(1); mfma16(1); __builtin_amdgcn_s_setprio(0);
        asm volatile("s_waitcnt vmcnt(0)" ::: "memory");
        __builtin_amdgcn_sched_barrier(0);
        __builtin_amdgcn_s_barrier();
    }
    {
        const int vb = (NT_ - 1) & 1;
        loadA(vb, 0); loadB(vb, 0, 0); mfma16(0);
        loadB(vb, 0, 1);               mfma16(1);
        loadA(vb, 1); loadB(vb, 1, 0); mfma16(0);
        loadB(vb, 1, 1);               mfma16(1);
    }

    // epilogue
    if (MODE == 2) {
        u16* oP = parts.p[blockIdx.z];
#pragma unroll
        for (int m = 0; m < 8; ++m)
#pragma unroll
            for (int r = 0; r < 4; ++r) {
                const int row = bm + gm * 128 + m * 16 + lg * 4 + r;
#pragma unroll
                for (int j = 0; j < 4; ++j)
                    oP[(size_t)row * N + bn + gn * 64 + j * 16 + l15] = f2b(acc[m][j][r]);
            }
    } else {
        const int cg = (bn + gn * 64) >> 10;
        const float* bp = (MODE == 0) ? (cg == 0 ? b0 : cg == 1 ? b1 : b2) : b0;
        const int cbase = (MODE == 0) ? ((bn + gn * 64) & 1023) : (bn + gn * 64);
        float bs[4];
#pragma unroll
        for (int j = 0; j < 4; ++j) bs[j] = bp[cbase + j * 16 + l15];
#pragma unroll
        for (int m = 0; m < 8; ++m)
#pragma unroll
            for (int r = 0; r < 4; ++r) {
                const int row = bm + gm * 128 + m * 16 + lg * 4 + r;
#pragma unroll
                for (int j = 0; j < 4; ++j) {
                    float v = acc[m][j][r] + bs[j];
                    if (MODE == 1) v = gelu_f(v);
                    outB[(size_t)row * N + bn + gn * 64 + j * 16 + l15] = f2b(v);
                }
            }
    }
}

// ---------------------------------------------------------------------------
// Split-K bf16 GEMM (m97 128x128 structure) — Wo only; bf16 partials.
// ---------------------------------------------------------------------------
__global__ __launch_bounds__(256) void gemm_splitk(
    const u16* __restrict__ A, const u16* __restrict__ Bt,
    PB parts, int N, int K, int kchunk)
{
    __shared__ __align__(16) u16 As[128 * 32];
    __shared__ __align__(16) u16 Bs[128 * 32];

    const int tid  = threadIdx.x;
    const int lane = tid & 63, wid = tid >> 6;
    const int l15  = lane & 15, lg = lane >> 4;
    const int wm   = (wid >> 1) * 64, wn = (wid & 1) * 64;
    const int bm   = blockIdx.y * 128, bn = blockIdx.x * 128;
    const int wbase16 = (tid & ~63) * 16;
    const int kt0 = blockIdx.z * kchunk, kt1 = kt0 + kchunk;
    u16* outP = parts.p[blockIdx.z];

    const int r0 = tid >> 2;
    const int c0 = (tid & 3) * 8;

    f32x4 acc[4][4];
#pragma unroll
    for (int i = 0; i < 4; ++i)
#pragma unroll
        for (int j = 0; j < 4; ++j) {
            acc[i][j][0] = 0.f; acc[i][j][1] = 0.f;
            acc[i][j][2] = 0.f; acc[i][j][3] = 0.f;
        }

    for (int kt = kt0; kt < kt1; kt += 32) {
        __syncthreads();
        gload16(A  + (size_t)(bm + r0)      * K + kt + c0, (char*)As + wbase16);
        gload16(A  + (size_t)(bm + r0 + 64) * K + kt + c0, (char*)As + wbase16 + 4096);
        gload16(Bt + (size_t)(bn + r0)      * K + kt + c0, (char*)Bs + wbase16);
        gload16(Bt + (size_t)(bn + r0 + 64) * K + kt + c0, (char*)Bs + wbase16 + 4096);
        __syncthreads();

        bf16_8 af[4], bfr[4];
#pragma unroll
        for (int f = 0; f < 4; ++f) {
            af[f]  = *(const bf16_8*)((const char*)As + (wm + f * 16 + l15) * 64 + lg * 16);
            bfr[f] = *(const bf16_8*)((const char*)Bs + (wn + f * 16 + l15) * 64 + lg * 16);
        }
#pragma unroll
        for (int i = 0; i < 4; ++i)
#pragma unroll
            for (int j = 0; j < 4; ++j)
                acc[i][j] = __builtin_amdgcn_mfma_f32_16x16x32_bf16(
                    af[i], bfr[j], acc[i][j], 0, 0, 0);
    }

#pragma unroll
    for (int i = 0; i < 4; ++i)
#pragma unroll
        for (int r = 0; r < 4; ++r) {
            const int row = bm + wm + i * 16 + lg * 4 + r;
#pragma unroll
            for (int j = 0; j < 4; ++j)
                outP[(size_t)row * N + bn + wn + j * 16 + l15] = f2b(acc[i][j][r]);
        }
}

// ---------------------------------------------------------------------------
// Reduce NPART bf16 partials + bias + residual, then LayerNorm over D=1024.
// ---------------------------------------------------------------------------
template<int NPART>
__global__ __launch_bounds__(256) void ln_reduce(
    PB parts, const float* __restrict__ bias, const float* __restrict__ res,
    const float* __restrict__ g, const float* __restrict__ b,
    float* __restrict__ O, u16* __restrict__ OB)
{
    const int row = blockIdx.x;
    const int tid = threadIdx.x;
    const size_t off = (size_t)row * D_ + tid * 4;

    float4 v = *(const float4*)(res + off);
    const float4 bi = *(const float4*)(bias + tid * 4);
    v.x += bi.x; v.y += bi.y; v.z += bi.z; v.w += bi.w;
#pragma unroll
    for (int p = 0; p < NPART; ++p) {
        const ushort4 t = *(const ushort4*)(parts.p[p] + off);
        v.x += b2f(t.x); v.y += b2f(t.y); v.z += b2f(t.z); v.w += b2f(t.w);
    }

    float s  = v.x + v.y + v.z + v.w;
    float sq = v.x * v.x + v.y * v.y + v.z * v.z + v.w * v.w;
#pragma unroll
    for (int o = 32; o; o >>= 1) {
        s  += __shfl_down(s, o);
        sq += __shfl_down(sq, o);
    }
    __shared__ float red[8];
    const int wid = tid >> 6, lane = tid & 63;
    if (lane == 0) { red[wid] = s; red[4 + wid] = sq; }
    __syncthreads();
    const float ts = red[0] + red[1] + red[2] + red[3];
    const float tq = red[4] + red[5] + red[6] + red[7];
    const float mu  = ts * (1.0f / D_);
    const float var = tq * (1.0f / D_) - mu * mu;
    const float rs  = rsqrtf(var + 1e-12f);

    const float4 gv = *(const float4*)(g + tid * 4);
    const float4 bv = *(const float4*)(b + tid * 4);
    float4 o;
    o.x = (v.x - mu) * rs * gv.x + bv.x;
    o.y = (v.y - mu) * rs * gv.y + bv.y;
    o.z = (v.z - mu) * rs * gv.z + bv.z;
    o.w = (v.w - mu) * rs * gv.w + bv.w;
    *(float4*)(O + off) = o;
    if (OB) {
        ushort4 ob;
        ob.x = f2b(o.x); ob.y = f2b(o.y); ob.z = f2b(o.z); ob.w = f2b(o.w);
        *(ushort4*)(OB + off) = ob;
    }
}

// ---------------------------------------------------------------------------
// Flash attention, bf16 MFMA, swapped-QK^T. 4 waves x 16 q = 64 q per block;
// grid 1024 -> up to 6 blocks/CU (was 2). Each thread stages 2x16B K + V
// chunks (idx = tid, tid+256; same kwoff/vwoff formulas as R6). T13 defer-max.
// XCD swizzle: wg%8 = head-group%8 (verified bijection).
// ---------------------------------------------------------------------------
__global__ __launch_bounds__(256) void attn_mfma(
    const u16* __restrict__ Qb, const u16* __restrict__ Kb,
    const u16* __restrict__ Vb, const float* __restrict__ mask,
    u16* __restrict__ ctxb, int qs)
{
    __shared__ __align__(16) char sm[24576];
    char* Ksm = sm;                 // [64 key][64 d], XOR-swizzled
    char* Vsm = sm + 8192;          // [4 d-panel][64 key][16 d]

    const int tid  = threadIdx.x;
    const int lane = tid & 63, wid = tid >> 6;
    char* Psm = sm + 16384 + wid * 2048;   // per-wave P[16 q][64 key], swizzled
    const int l15 = lane & 15, lg = lane >> 4;

    // XCD-chunked bijective swizzle: g = (wg&7) + 8*((wg>>3)&7), qb = wg>>6
    const int wg = blockIdx.x;
    const int g  = (wg & 7) + 8 * ((wg >> 3) & 7);
    const int qb = wg >> 6;
    const int b  = g >> 4;
    const int h  = g & 15;

    const int q0 = qb * 64 + wid * 16;
    const size_t inhead  = ((size_t)b * S_) * qs + (size_t)h * 64;
    const size_t outhead = ((size_t)b * S_) * D_ + (size_t)h * 64;

    const u16* Qrow = Qb + inhead + (size_t)(q0 + l15) * qs;
    const bf16_8 qf0 = *(const bf16_8*)(Qrow + lg * 8);
    const bf16_8 qf1 = *(const bf16_8*)(Qrow + 32 + lg * 8);

    f32x4 ctx[4];
#pragma unroll
    for (int i = 0; i < 4; ++i) { ctx[i][0]=0.f; ctx[i][1]=0.f; ctx[i][2]=0.f; ctx[i][3]=0.f; }
    float m_r = -1e30f, l_r = 0.f;

    // staging: 256 threads x 2 chunks of 16B for K and V each
    const int sk0 = tid >> 3;                 // chunk 0: keys 0..31
    const int sk1 = sk0 + 32;                 // chunk 1: keys 32..63
    const int sd0 = (tid & 7) * 8;
    const int xo_p = (l15 & 7) << 4;
    const int kw0 = sk0 * 128 + ((sd0 * 2) ^ ((sk0 & 7) << 4));
    const int kw1 = sk1 * 128 + ((sd0 * 2) ^ ((sk1 & 7) << 4));
    const int vw0 = (sd0 >> 4) * 2048 + sk0 * 32 + ((sd0 & 8) << 1);
    const int vw1 = (sd0 >> 4) * 2048 + sk1 * 32 + ((sd0 & 8) << 1);

    const __attribute__((address_space(3))) char* vtr =
        (const __attribute__((address_space(3))) char*)(Vsm + lg * 256 + l15 * 2);

    bf16_8 kreg0 = *(const bf16_8*)(Kb + inhead + (size_t)sk0 * qs + sd0);
    bf16_8 kreg1 = *(const bf16_8*)(Kb + inhead + (size_t)sk1 * qs + sd0);
    bf16_8 vreg0 = *(const bf16_8*)(Vb + inhead + (size_t)sk0 * qs + sd0);
    bf16_8 vreg1 = *(const bf16_8*)(Vb + inhead + (size_t)sk1 * qs + sd0);

    for (int t = 0; t < S_ / 64; ++t) {
        __syncthreads();
        *(bf16_8*)(Ksm + kw0) = kreg0;
        *(bf16_8*)(Ksm + kw1) = kreg1;
        *(bf16_8*)(Vsm + vw0) = vreg0;
        *(bf16_8*)(Vsm + vw1) = vreg1;
        __syncthreads();
        if (t < S_ / 64 - 1) {
            const size_t base = inhead + (size_t)((t + 1) * 64) * qs + sd0;
            kreg0 = *(const bf16_8*)(Kb + base + (size_t)sk0 * qs);
            kreg1 = *(const bf16_8*)(Kb + base + (size_t)sk1 * qs);
            vreg0 = *(const bf16_8*)(Vb + base + (size_t)sk0 * qs);
            vreg1 = *(const bf16_8*)(Vb + base + (size_t)sk1 * qs);
        }

        // S^T = K.Q^T: lane holds 16 scores for q=l15 (keys kf*16+lg*4+r)
        f32x4 sc[4];
#pragma unroll
        for (int kf = 0; kf < 4; ++kf) {
            const int key = kf * 16 + l15;
            f32x4 a; a[0]=0.f; a[1]=0.f; a[2]=0.f; a[3]=0.f;
            const bf16_8 kA = *(const bf16_8*)(Ksm + key * 128 + ((lg * 16)      ^ xo_p));
            a = __builtin_amdgcn_mfma_f32_16x16x32_bf16(kA, qf0, a, 0, 0, 0);
            const bf16_8 kB = *(const bf16_8*)(Ksm + key * 128 + ((64 + lg * 16) ^ xo_p));
            a = __builtin_amdgcn_mfma_f32_16x16x32_bf16(kB, qf1, a, 0, 0, 0);
            sc[kf] = a;
        }

        // lane-local softmax with T13 defer-max
        float p[16];
        float tmax = -1e30f;
#pragma unroll
        for (int kf = 0; kf < 4; ++kf) {
            const float4 mk = *(const float4*)(mask + (size_t)b * S_ + t * 64 + kf * 16 + lg * 4);
#pragma unroll
            for (int r = 0; r < 4; ++r) {
                const float mkr = (r == 0) ? mk.x : (r == 1) ? mk.y : (r == 2) ? mk.z : mk.w;
                p[kf * 4 + r] = sc[kf][r] * 0.125f + mkr;
                tmax = fmaxf(tmax, p[kf * 4 + r]);
            }
        }
        tmax = fmaxf(tmax, __shfl_xor(tmax, 16));
        tmax = fmaxf(tmax, __shfl_xor(tmax, 32));

        if (!__all(tmax <= m_r + 8.0f)) {
            const float mnew = fmaxf(m_r, tmax);
            const float scl  = __expf(m_r - mnew);
            m_r = mnew;
            l_r *= scl;
#pragma unroll
            for (int fd = 0; fd < 4; ++fd)
#pragma unroll
                for (int r = 0; r < 4; ++r) ctx[fd][r] *= scl;
        }

        float psum = 0.f;
#pragma unroll
        for (int i = 0; i < 16; ++i) {
            p[i] = __expf(p[i] - m_r);
            psum += p[i];
        }
        psum += __shfl_xor(psum, 16);
        psum += __shfl_xor(psum, 32);
        l_r += psum;

        // store P row q=l15 (8 x ushort2, swizzled)
#pragma unroll
        for (int kf = 0; kf < 4; ++kf)
#pragma unroll
            for (int rr = 0; rr < 2; ++rr) {
                ushort2 wv;
                wv.x = f2b(p[kf * 4 + 2 * rr]);
                wv.y = f2b(p[kf * 4 + 2 * rr + 1]);
                *(ushort2*)(Psm + l15 * 128 +
                            (((kf * 16 + lg * 4 + 2 * rr) * 2) ^ xo_p)) = wv;
            }
        asm volatile("s_waitcnt lgkmcnt(0)" ::: "memory");

        // ctx^T += V^T . P^T; V fragments via HW transpose-read
#pragma unroll
        for (int s = 0; s < 2; ++s) {
            const bf16_8 pf = *(const bf16_8*)(Psm + l15 * 128 +
                                ((s * 64 + lg * 16) ^ xo_p));
            const __attribute__((address_space(3))) char* a3 = vtr + s * 1024;
            u32x2 r0, r1, r2, r3, r4, r5, r6, r7;
            asm volatile(
                "ds_read_b64_tr_b16 %0, %8 offset:0\n\t"
                "ds_read_b64_tr_b16 %1, %8 offset:128\n\t"
                "ds_read_b64_tr_b16 %2, %8 offset:2048\n\t"
                "ds_read_b64_tr_b16 %3, %8 offset:2176\n\t"
                "ds_read_b64_tr_b16 %4, %8 offset:4096\n\t"
                "ds_read_b64_tr_b16 %5, %8 offset:4224\n\t"
                "ds_read_b64_tr_b16 %6, %8 offset:6144\n\t"
                "ds_read_b64_tr_b16 %7, %8 offset:6272\n\t"
                "s_waitcnt lgkmcnt(0)"
                : "=&v"(r0), "=&v"(r1), "=&v"(r2), "=&v"(r3),
                  "=&v"(r4), "=&v"(r5), "=&v"(r6), "=&v"(r7)
                : "v"(a3));
            union Cv { unsigned u[4]; bf16_8 v; };
            Cv c0; c0.u[0] = r0.x; c0.u[1] = r0.y; c0.u[2] = r1.x; c0.u[3] = r1.y;
            Cv c1; c1.u[0] = r2.x; c1.u[1] = r2.y; c1.u[2] = r3.x; c1.u[3] = r3.y;
            Cv c2; c2.u[0] = r4.x; c2.u[1] = r4.y; c2.u[2] = r5.x; c2.u[3] = r5.y;
            Cv c3; c3.u[0] = r6.x; c3.u[1] = r6.y; c3.u[2] = r7.x; c3.u[3] = r7.y;
            ctx[0] = __builtin_amdgcn_mfma_f32_16x16x32_bf16(c0.v, pf, ctx[0], 0, 0, 0);
            ctx[1] = __builtin_amdgcn_mfma_f32_16x16x32_bf16(c1.v, pf, ctx[1], 0, 0, 0);
            ctx[2] = __builtin_amdgcn_mfma_f32_16x16x32_bf16(c2.v, pf, ctx[2], 0, 0, 0);
            ctx[3] = __builtin_amdgcn_mfma_f32_16x16x32_bf16(c3.v, pf, ctx[3], 0, 0, 0);
        }
    }

    const float inv = 1.f / l_r;
    const size_t qrow = outhead + (size_t)(q0 + l15) * D_;
#pragma unroll
    for (int fd = 0; fd < 4; ++fd) {
        ushort4 o;
        o.x = f2b(ctx[fd][0] * inv);
        o.y = f2b(ctx[fd][1] * inv);
        o.z = f2b(ctx[fd][2] * inv);
        o.w = f2b(ctx[fd][3] * inv);
        *(ushort4*)(ctxb + qrow + fd * 16 + lg * 4) = o;
    }
}

// ---------------------------------------------------------------------------
extern "C" void kernel_launch(void* const* d_in, const int* in_sizes, int n_in,
                              void* d_out, int out_size, void* d_ws, size_t ws_size,
                              hipStream_t stream)
{
    const float* h    = (const float*)d_in[0];
    const float* mask = (const float*)d_in[1];
    const float* Wq   = (const float*)d_in[2];
    const float* bq   = (const float*)d_in[3];
    const float* Wk   = (const float*)d_in[4];
    const float* bk   = (const float*)d_in[5];
    const float* Wv   = (const float*)d_in[6];
    const float* bv   = (const float*)d_in[7];
    const float* Wo   = (const float*)d_in[8];
    const float* bo   = (const float*)d_in[9];
    const float* ln1g = (const float*)d_in[10];
    const float* ln1b = (const float*)d_in[11];
    const float* Wi   = (const float*)d_in[12];
    const float* bi   = (const float*)d_in[13];
    const float* Wout = (const float*)d_in[14];
    const float* bout = (const float*)d_in[15];
    const float* ln2g = (const float*)d_in[16];
    const float* ln2b = (const float*)d_in[17];
    float* out = (float*)d_out;

    char* w = (char*)d_ws;
    const size_t MiB = 1ull << 20;
    // liveness-packed layout, peak 104 MiB:
    u16*   Woutt  = (u16*)(w + 0);             // [0,8)   live to FFN2
    u16*   Wit    = (u16*)(w + 8 * MiB);       // [8,16)  live to FFN1
    u16*   hb     = (u16*)(w + 16 * MiB);      // [16,24) dead after QKV
    u16*   woP0   = (u16*)(w + 16 * MiB);      //   then Wo partial 0 (bf16)
    u16*   ffP1   = (u16*)(w + 16 * MiB);      //   then FFN2 partial 1
    u16*   Wqkvt  = (u16*)(w + 24 * MiB);      // [24,30) dead after QKV
    u16*   ffP2   = (u16*)(w + 24 * MiB);      //   then FFN2 partial 2
    u16*   Wot    = (u16*)(w + 30 * MiB);      // [30,32) dead after Wo-splitk
    u16*   QKVb   = (u16*)(w + 32 * MiB);      // [32,56) dead after attn
    u16*   woP1   = (u16*)(w + 32 * MiB);      //   then Wo partial 1
    u16*   ffP3   = (u16*)(w + 32 * MiB);      //   then FFN2 partial 3
    float* attnF  = (float*)(w + 40 * MiB);    // [40,56) live to ln2
    u16*   attnB  = (u16*)(w + 56 * MiB);      // [56,64) dead after FFN1
    u16*   interB = (u16*)(w + 64 * MiB);      // [64,96) dead after FFN2
    u16*   ctxb   = (u16*)(w + 96 * MiB);      // [96,104) dead after Wo-splitk
    u16*   ffP0   = (u16*)(w + 96 * MiB);      //   then FFN2 partial 0

    const dim3 blk(256);
    PB zp; zp.p[0] = zp.p[1] = zp.p[2] = zp.p[3] = nullptr;

    // fused prep: h -> bf16 + 6 weight transposes, one dispatch
    Prep pp;
    pp.s[0] = Wq;   pp.d[0] = Wqkvt;                 pp.K[0] = D_; pp.N[0] = D_;
    pp.s[1] = Wk;   pp.d[1] = Wqkvt + 1024 * 1024;   pp.K[1] = D_; pp.N[1] = D_;
    pp.s[2] = Wv;   pp.d[2] = Wqkvt + 2 * 1024 * 1024; pp.K[2] = D_; pp.N[2] = D_;
    pp.s[3] = Wo;   pp.d[3] = Wot;                   pp.K[3] = D_; pp.N[3] = D_;
    pp.s[4] = Wi;   pp.d[4] = Wit;                   pp.K[4] = D_; pp.N[4] = I_;
    pp.s[5] = Wout; pp.d[5] = Woutt;                 pp.K[5] = I_; pp.N[5] = D_;
    pp.cin  = (const float4*)h;
    pp.cout = (ushort4*)hb;
    prep_all<<<dim3(128, 32, 7), blk, 0, stream>>>(pp);

    // fused QKV projection: 256^2 8-phase, grid (12,16)
    gemm256<0><<<dim3(12, 16, 1), dim3(512), 0, stream>>>(
        hb, Wqkvt, bq, bk, bv, QKVb, zp, 3072, 1024, 1024);

    // attention: 1024 blocks x 256 threads (6 blocks/CU), XCD-chunked swizzle
    attn_mfma<<<dim3(1024), dim3(256), 0, stream>>>(
        QKVb, QKVb + 1024, QKVb + 2048, mask, ctxb, 3072);

    // Wo projection, split-K x2 -> bf16 partials; reduce+bias+res(h)+LN1
    PB woP; woP.p[0] = woP0; woP.p[1] = woP1; woP.p[2] = nullptr; woP.p[3] = nullptr;
    gemm_splitk<<<dim3(8, 32, 2), blk, 0, stream>>>(ctxb, Wot, woP, D_, D_, 512);
    ln_reduce<2><<<dim3(M_), blk, 0, stream>>>(woP, bo, h, ln1g, ln1b, attnF, attnB);

    // FFN1: erf-GELU GEMM, 256^2 8-phase, grid (16,16)
    gemm256<1><<<dim3(16, 16, 1), dim3(512), 0, stream>>>(
        attnB, Wit, bi, nullptr, nullptr, interB, zp, 4096, 1024, 1024);

    // FFN2: 256^2 8-phase split-K x4 -> bf16 partials; reduce+bias+res+LN2 -> out
    PB ffP; ffP.p[0] = ffP0; ffP.p[1] = ffP1; ffP.p[2] = ffP2; ffP.p[3] = ffP3;
    gemm256<2><<<dim3(4, 16, 4), dim3(512), 0, stream>>>(
        interB, Woutt, nullptr, nullptr, nullptr, nullptr, ffP, 1024, 4096, 4096);
    ln_reduce<4><<<dim3(M_), blk, 0, stream>>>(ffP, bout, attnF, ln2g, ln2b, out, nullptr);
}

// Round 13
// 209.809 us; speedup vs baseline: 1.1036x; 1.1036x over previous
//
#include <hip/hip_runtime.h>
#include <hip/hip_bf16.h>
#include <math.h>

#define B_ 4
#define S_ 1024
#define D_ 1024
#define NH_ 16
#define HD_ 64
#define I_ 4096
#define M_ (B_*S_)

typedef __bf16 bf16_8 __attribute__((ext_vector_type(8)));
typedef float f32x4 __attribute__((ext_vector_type(4)));
typedef unsigned int u32x2 __attribute__((ext_vector_type(2)));
typedef unsigned short u16;

struct PB { u16* p[4]; };
struct Prep {
    const float* s[6]; u16* d[6]; int K[6]; int N[6];
    const float4* cin; ushort4* cout;
};

__device__ __forceinline__ u16 f2b(float x) {
    __hip_bfloat16 h = __float2bfloat16(x);
    return *reinterpret_cast<u16*>(&h);
}
__device__ __forceinline__ float b2f(u16 x) {
    return __uint_as_float(((unsigned)x) << 16);
}

__device__ __forceinline__ void gload16(const void* g, void* l) {
    __builtin_amdgcn_global_load_lds(
        (const __attribute__((address_space(1))) void*)g,
        (__attribute__((address_space(3))) void*)l, 16, 0, 0);
}

// exact-GELU via A&S 7.1.26 erf poly (max abs err 1.5e-7, no systematic bias)
__device__ __forceinline__ float gelu_f(float v) {
    const float z  = v * 0.70710678118654752f;
    const float az = fabsf(z);
    const float t  = __fdividef(1.0f, 1.0f + 0.3275911f * az);
    const float poly = t * (0.254829592f + t * (-0.284496736f +
                       t * (1.421413741f + t * (-1.453152027f + t * 1.061405429f))));
    const float erfa = 1.0f - poly * __expf(-z * z);
    const float erfv = copysignf(erfa, z);
    return 0.5f * v * (1.0f + erfv);
}

// ---------------------------------------------------------------------------
// Fused prep: z=0..5 -> W[K][N] fp32 -> Wt[N][K] bf16 transposes;
// z=6 -> h fp32 -> bf16 convert. Grid (128, 32, 7); surplus tiles early-exit.
// ---------------------------------------------------------------------------
__global__ __launch_bounds__(256) void prep_all(Prep p)
{
    const int tid = threadIdx.x;
    const int z = blockIdx.z;
    const int tile = blockIdx.y * 128 + blockIdx.x;

    if (z == 6) {
        const int i = tile * 256 + tid;
        float4 v = p.cin[i];
        ushort4 o;
        o.x = f2b(v.x); o.y = f2b(v.y); o.z = f2b(v.z); o.w = f2b(v.w);
        p.cout[i] = o;
        return;
    }

    const int K = p.K[z], N = p.N[z];
    const int ntile = N >> 5;
    if (tile >= (K >> 5) * ntile) return;
    const int k0 = (tile / ntile) * 32, n0 = (tile % ntile) * 32;
    const float* in = p.s[z];
    u16* out = p.d[z];

    __shared__ float t[32][33];
#pragma unroll
    for (int i = 0; i < 4; ++i) {
        int idx = i * 256 + tid;
        int r = idx >> 5, c = idx & 31;
        t[r][c] = in[(size_t)(k0 + r) * N + n0 + c];
    }
    __syncthreads();
    const int rr = tid >> 3, cc0 = (tid & 7) * 4;
    ushort4 o;
    o.x = f2b(t[cc0 + 0][rr]);
    o.y = f2b(t[cc0 + 1][rr]);
    o.z = f2b(t[cc0 + 2][rr]);
    o.w = f2b(t[cc0 + 3][rr]);
    *(ushort4*)(out + (size_t)(n0 + rr) * K + k0 + cc0) = o;
}

// ---------------------------------------------------------------------------
// 256x256 8-phase bf16 MFMA GEMM (runtime strides).
// MODE 0: +bias(QKV-select) -> bf16.  MODE 1: +bias+erf-GELU -> bf16.
// MODE 2: split-K bf16 partial (blockIdx.z selects chunk+partial buffer).
// ---------------------------------------------------------------------------
#define NT_ 16

template<int MODE>
__global__ __launch_bounds__(512, 2) void gemm256(
    const u16* __restrict__ A, const u16* __restrict__ Bt,
    const float* __restrict__ b0, const float* __restrict__ b1,
    const float* __restrict__ b2,
    u16* __restrict__ outB, PB parts, int N, int sA, int sB)
{
    __shared__ __align__(16) char sm[131072];

    const int tid  = threadIdx.x;
    const int lane = tid & 63, wid = tid >> 6;
    const int l15  = lane & 15, lg = lane >> 4;
    const int gm   = wid >> 2, gn = wid & 3;
    const int bm   = blockIdx.y * 256, bn = blockIdx.x * 256;
    const int koff = (MODE == 2) ? blockIdx.z * 1024 : 0;

    const int srow = (wid << 3) + (lane >> 3);
    const int skb  = ((lane & 7) << 4) ^ (((lane >> 3) & 7) << 4);
    const int scol = skb >> 1;
    const int xm   = (l15 & 7) << 4;

    f32x4 acc[8][4];
#pragma unroll
    for (int m = 0; m < 8; ++m)
#pragma unroll
        for (int j = 0; j < 4; ++j) {
            acc[m][j][0] = 0.f; acc[m][j][1] = 0.f;
            acc[m][j][2] = 0.f; acc[m][j][3] = 0.f;
        }

    auto stageA = [&](int v, int h) {
        const u16* src = A + (size_t)(bm + h * 128 + srow) * sA + koff + v * 64 + scol;
        char* dst = sm + ((v & 1) * 65536 + h * 16384 + wid * 1024);
        gload16(src, dst);
        gload16(src + (size_t)64 * sA, dst + 8192);
    };
    auto stageB = [&](int v, int h) {
        const u16* src = Bt + (size_t)(bn + h * 128 + srow) * sB + koff + v * 64 + scol;
        char* dst = sm + ((v & 1) * 65536 + 32768 + h * 16384 + wid * 1024);
        gload16(src, dst);
        gload16(src + (size_t)64 * sB, dst + 8192);
    };

    bf16_8 a[8], bb[2];
    auto loadA = [&](int vb, int s) {
        const char* base = sm + (vb * 65536 + gm * 16384);
#pragma unroll
        for (int m = 0; m < 8; ++m)
            a[m] = *(const bf16_8*)(base + (m * 16 + l15) * 128 +
                                    ((s * 64 + lg * 16) ^ xm));
    };
    auto loadB = [&](int vb, int s, int np) {
        const char* base = sm + (vb * 65536 + 32768 + (gn >> 1) * 16384);
#pragma unroll
        for (int j = 0; j < 2; ++j)
            bb[j] = *(const bf16_8*)(base + ((gn & 1) * 64 + (np * 2 + j) * 16 + l15) * 128 +
                                     ((s * 64 + lg * 16) ^ xm));
    };
    auto mfma16 = [&](int np) {
#pragma unroll
        for (int m = 0; m < 8; ++m)
#pragma unroll
            for (int j = 0; j < 2; ++j)
                acc[m][np * 2 + j] = __builtin_amdgcn_mfma_f32_16x16x32_bf16(
                    a[m], bb[j], acc[m][np * 2 + j], 0, 0, 0);
    };

    // prologue
    stageA(0, 0); stageA(0, 1);
    stageB(0, 0); stageB(0, 1);
    stageA(1, 0); stageA(1, 1);
    asm volatile("s_waitcnt vmcnt(4)" ::: "memory");
    __builtin_amdgcn_sched_barrier(0);
    __builtin_amdgcn_s_barrier();

    for (int v = 0; v < NT_ - 2; ++v) {
        const int vb = v & 1;
        loadA(vb, 0); loadB(vb, 0, 0);
        stageB(v + 1, 0); stageB(v + 1, 1);
        __builtin_amdgcn_s_barrier();
        asm volatile("s_waitcnt lgkmcnt(0)" ::: "memory");
        __builtin_amdgcn_s_setprio(1); mfma16(0); __builtin_amdgcn_s_setprio(0);
        __builtin_amdgcn_s_barrier();
        loadB(vb, 0, 1);
        __builtin_amdgcn_s_barrier();
        asm volatile("s_waitcnt lgkmcnt(0)" ::: "memory");
        __builtin_amdgcn_s_setprio(1); mfma16(1); __builtin_amdgcn_s_setprio(0);
        __builtin_amdgcn_s_barrier();
        loadA(vb, 1); loadB(vb, 1, 0);
        __builtin_amdgcn_s_barrier();
        asm volatile("s_waitcnt lgkmcnt(0)" ::: "memory");
        __builtin_amdgcn_s_setprio(1); mfma16(0); __builtin_amdgcn_s_setprio(0);
        __builtin_amdgcn_s_barrier();
        loadB(vb, 1, 1);
        stageA(v + 2, 0); stageA(v + 2, 1);
        __builtin_amdgcn_s_barrier();
        asm volatile("s_waitcnt lgkmcnt(0)" ::: "memory");
        __builtin_amdgcn_s_setprio(1); mfma16(1); __builtin_amdgcn_s_setprio(0);
        asm volatile("s_waitcnt vmcnt(4)" ::: "memory");
        __builtin_amdgcn_sched_barrier(0);
        __builtin_amdgcn_s_barrier();
    }
    {
        const int vb = (NT_ - 2) & 1;
        loadA(vb, 0); loadB(vb, 0, 0);
        stageB(NT_ - 1, 0); stageB(NT_ - 1, 1);
        __builtin_amdgcn_s_barrier();
        asm volatile("s_waitcnt lgkmcnt(0)" ::: "memory");
        __builtin_amdgcn_s_setprio(1); mfma16(0); __builtin_amdgcn_s_setprio(0);
        __builtin_amdgcn_s_barrier();
        loadB(vb, 0, 1);
        __builtin_amdgcn_s_barrier();
        asm volatile("s_waitcnt lgkmcnt(0)" ::: "memory");
        __builtin_amdgcn_s_setprio(1); mfma16(1); __builtin_amdgcn_s_setprio(0);
        __builtin_amdgcn_s_barrier();
        loadA(vb, 1); loadB(vb, 1, 0);
        __builtin_amdgcn_s_barrier();
        asm volatile("s_waitcnt lgkmcnt(0)" ::: "memory");
        __builtin_amdgcn_s_setprio(1); mfma16(0); __builtin_amdgcn_s_setprio(0);
        __builtin_amdgcn_s_barrier();
        loadB(vb, 1, 1);
        __builtin_amdgcn_s_barrier();
        asm volatile("s_waitcnt lgkmcnt(0)" ::: "memory");
        __builtin_amdgcn_s_setprio(1); mfma16(1); __builtin_amdgcn_s_setprio(0);
        asm volatile("s_waitcnt vmcnt(0)" ::: "memory");
        __builtin_amdgcn_sched_barrier(0);
        __builtin_amdgcn_s_barrier();
    }
    {
        const int vb = (NT_ - 1) & 1;
        loadA(vb, 0); loadB(vb, 0, 0); mfma16(0);
        loadB(vb, 0, 1);               mfma16(1);
        loadA(vb, 1); loadB(vb, 1, 0); mfma16(0);
        loadB(vb, 1, 1);               mfma16(1);
    }

    // epilogue
    if (MODE == 2) {
        u16* oP = parts.p[blockIdx.z];
#pragma unroll
        for (int m = 0; m < 8; ++m)
#pragma unroll
            for (int r = 0; r < 4; ++r) {
                const int row = bm + gm * 128 + m * 16 + lg * 4 + r;
#pragma unroll
                for (int j = 0; j < 4; ++j)
                    oP[(size_t)row * N + bn + gn * 64 + j * 16 + l15] = f2b(acc[m][j][r]);
            }
    } else {
        const int cg = (bn + gn * 64) >> 10;
        const float* bp = (MODE == 0) ? (cg == 0 ? b0 : cg == 1 ? b1 : b2) : b0;
        const int cbase = (MODE == 0) ? ((bn + gn * 64) & 1023) : (bn + gn * 64);
        float bs[4];
#pragma unroll
        for (int j = 0; j < 4; ++j) bs[j] = bp[cbase + j * 16 + l15];
#pragma unroll
        for (int m = 0; m < 8; ++m)
#pragma unroll
            for (int r = 0; r < 4; ++r) {
                const int row = bm + gm * 128 + m * 16 + lg * 4 + r;
#pragma unroll
                for (int j = 0; j < 4; ++j) {
                    float v = acc[m][j][r] + bs[j];
                    if (MODE == 1) v = gelu_f(v);
                    outB[(size_t)row * N + bn + gn * 64 + j * 16 + l15] = f2b(v);
                }
            }
    }
}

// ---------------------------------------------------------------------------
// Split-K bf16 GEMM (m97 128x128 structure) — Wo only; bf16 partials.
// ---------------------------------------------------------------------------
__global__ __launch_bounds__(256) void gemm_splitk(
    const u16* __restrict__ A, const u16* __restrict__ Bt,
    PB parts, int N, int K, int kchunk)
{
    __shared__ __align__(16) u16 As[128 * 32];
    __shared__ __align__(16) u16 Bs[128 * 32];

    const int tid  = threadIdx.x;
    const int lane = tid & 63, wid = tid >> 6;
    const int l15  = lane & 15, lg = lane >> 4;
    const int wm   = (wid >> 1) * 64, wn = (wid & 1) * 64;
    const int bm   = blockIdx.y * 128, bn = blockIdx.x * 128;
    const int wbase16 = (tid & ~63) * 16;
    const int kt0 = blockIdx.z * kchunk, kt1 = kt0 + kchunk;
    u16* outP = parts.p[blockIdx.z];

    const int r0 = tid >> 2;
    const int c0 = (tid & 3) * 8;

    f32x4 acc[4][4];
#pragma unroll
    for (int i = 0; i < 4; ++i)
#pragma unroll
        for (int j = 0; j < 4; ++j) {
            acc[i][j][0] = 0.f; acc[i][j][1] = 0.f;
            acc[i][j][2] = 0.f; acc[i][j][3] = 0.f;
        }

    for (int kt = kt0; kt < kt1; kt += 32) {
        __syncthreads();
        gload16(A  + (size_t)(bm + r0)      * K + kt + c0, (char*)As + wbase16);
        gload16(A  + (size_t)(bm + r0 + 64) * K + kt + c0, (char*)As + wbase16 + 4096);
        gload16(Bt + (size_t)(bn + r0)      * K + kt + c0, (char*)Bs + wbase16);
        gload16(Bt + (size_t)(bn + r0 + 64) * K + kt + c0, (char*)Bs + wbase16 + 4096);
        __syncthreads();

        bf16_8 af[4], bfr[4];
#pragma unroll
        for (int f = 0; f < 4; ++f) {
            af[f]  = *(const bf16_8*)((const char*)As + (wm + f * 16 + l15) * 64 + lg * 16);
            bfr[f] = *(const bf16_8*)((const char*)Bs + (wn + f * 16 + l15) * 64 + lg * 16);
        }
#pragma unroll
        for (int i = 0; i < 4; ++i)
#pragma unroll
            for (int j = 0; j < 4; ++j)
                acc[i][j] = __builtin_amdgcn_mfma_f32_16x16x32_bf16(
                    af[i], bfr[j], acc[i][j], 0, 0, 0);
    }

#pragma unroll
    for (int i = 0; i < 4; ++i)
#pragma unroll
        for (int r = 0; r < 4; ++r) {
            const int row = bm + wm + i * 16 + lg * 4 + r;
#pragma unroll
            for (int j = 0; j < 4; ++j)
                outP[(size_t)row * N + bn + wn + j * 16 + l15] = f2b(acc[i][j][r]);
        }
}

// ---------------------------------------------------------------------------
// Reduce NPART bf16 partials + bias + residual, then LayerNorm over D=1024.
// ---------------------------------------------------------------------------
template<int NPART>
__global__ __launch_bounds__(256) void ln_reduce(
    PB parts, const float* __restrict__ bias, const float* __restrict__ res,
    const float* __restrict__ g, const float* __restrict__ b,
    float* __restrict__ O, u16* __restrict__ OB)
{
    const int row = blockIdx.x;
    const int tid = threadIdx.x;
    const size_t off = (size_t)row * D_ + tid * 4;

    float4 v = *(const float4*)(res + off);
    const float4 bi = *(const float4*)(bias + tid * 4);
    v.x += bi.x; v.y += bi.y; v.z += bi.z; v.w += bi.w;
#pragma unroll
    for (int p = 0; p < NPART; ++p) {
        const ushort4 t = *(const ushort4*)(parts.p[p] + off);
        v.x += b2f(t.x); v.y += b2f(t.y); v.z += b2f(t.z); v.w += b2f(t.w);
    }

    float s  = v.x + v.y + v.z + v.w;
    float sq = v.x * v.x + v.y * v.y + v.z * v.z + v.w * v.w;
#pragma unroll
    for (int o = 32; o; o >>= 1) {
        s  += __shfl_down(s, o);
        sq += __shfl_down(sq, o);
    }
    __shared__ float red[8];
    const int wid = tid >> 6, lane = tid & 63;
    if (lane == 0) { red[wid] = s; red[4 + wid] = sq; }
    __syncthreads();
    const float ts = red[0] + red[1] + red[2] + red[3];
    const float tq = red[4] + red[5] + red[6] + red[7];
    const float mu  = ts * (1.0f / D_);
    const float var = tq * (1.0f / D_) - mu * mu;
    const float rs  = rsqrtf(var + 1e-12f);

    const float4 gv = *(const float4*)(g + tid * 4);
    const float4 bv = *(const float4*)(b + tid * 4);
    float4 o;
    o.x = (v.x - mu) * rs * gv.x + bv.x;
    o.y = (v.y - mu) * rs * gv.y + bv.y;
    o.z = (v.z - mu) * rs * gv.z + bv.z;
    o.w = (v.w - mu) * rs * gv.w + bv.w;
    *(float4*)(O + off) = o;
    if (OB) {
        ushort4 ob;
        ob.x = f2b(o.x); ob.y = f2b(o.y); ob.z = f2b(o.z); ob.w = f2b(o.w);
        *(ushort4*)(OB + off) = ob;
    }
}

// ---------------------------------------------------------------------------
// Flash attention, bf16 MFMA, swapped-QK^T. R6-proven 8-wave structure.
// ---------------------------------------------------------------------------
__global__ __launch_bounds__(512) void attn_mfma(
    const u16* __restrict__ Qb, const u16* __restrict__ Kb,
    const u16* __restrict__ Vb, const float* __restrict__ mask,
    u16* __restrict__ ctxb, int qs)
{
    __shared__ __align__(16) char sm[32768];
    char* Ksm = sm;
    char* Vsm = sm + 8192;

    const int tid  = threadIdx.x;
    const int lane = tid & 63, wid = tid >> 6;
    char* Psm = sm + 16384 + wid * 2048;
    const int l15 = lane & 15, lg = lane >> 4;

    const int wg  = blockIdx.x;
    const int swz = (wg & 7) * 64 + (wg >> 3);
    const int b   = swz >> 7;
    const int h   = (swz >> 3) & 15;
    const int qb  = swz & 7;

    const int q0 = qb * 128 + wid * 16;
    const size_t inhead  = ((size_t)b * S_) * qs + (size_t)h * 64;
    const size_t outhead = ((size_t)b * S_) * D_ + (size_t)h * 64;

    const u16* Qrow = Qb + inhead + (size_t)(q0 + l15) * qs;
    const bf16_8 qf0 = *(const bf16_8*)(Qrow + lg * 8);
    const bf16_8 qf1 = *(const bf16_8*)(Qrow + 32 + lg * 8);

    f32x4 ctx[4];
#pragma unroll
    for (int i = 0; i < 4; ++i) { ctx[i][0]=0.f; ctx[i][1]=0.f; ctx[i][2]=0.f; ctx[i][3]=0.f; }
    float m_r = -1e30f, l_r = 0.f;

    const int skey = tid >> 3;
    const int sd0  = (tid & 7) * 8;
    const int xo_p = (l15 & 7) << 4;
    const int kwoff = skey * 128 + ((sd0 * 2) ^ ((skey & 7) << 4));
    const int vwoff = (sd0 >> 4) * 2048 + skey * 32 + ((sd0 & 8) << 1);

    const __attribute__((address_space(3))) char* vtr =
        (const __attribute__((address_space(3))) char*)(Vsm + lg * 256 + l15 * 2);

    bf16_8 kreg = *(const bf16_8*)(Kb + inhead + (size_t)skey * qs + sd0);
    bf16_8 vreg = *(const bf16_8*)(Vb + inhead + (size_t)skey * qs + sd0);

    for (int t = 0; t < S_ / 64; ++t) {
        __syncthreads();
        *(bf16_8*)(Ksm + kwoff) = kreg;
        *(bf16_8*)(Vsm + vwoff) = vreg;
        __syncthreads();
        if (t < S_ / 64 - 1) {
            const size_t noff = inhead + (size_t)((t + 1) * 64 + skey) * qs + sd0;
            kreg = *(const bf16_8*)(Kb + noff);
            vreg = *(const bf16_8*)(Vb + noff);
        }

        f32x4 sc[4];
#pragma unroll
        for (int kf = 0; kf < 4; ++kf) {
            const int key = kf * 16 + l15;
            f32x4 a; a[0]=0.f; a[1]=0.f; a[2]=0.f; a[3]=0.f;
            const bf16_8 kA = *(const bf16_8*)(Ksm + key * 128 + ((lg * 16)      ^ xo_p));
            a = __builtin_amdgcn_mfma_f32_16x16x32_bf16(kA, qf0, a, 0, 0, 0);
            const bf16_8 kB = *(const bf16_8*)(Ksm + key * 128 + ((64 + lg * 16) ^ xo_p));
            a = __builtin_amdgcn_mfma_f32_16x16x32_bf16(kB, qf1, a, 0, 0, 0);
            sc[kf] = a;
        }

        float p[16];
        float tmax = -1e30f;
#pragma unroll
        for (int kf = 0; kf < 4; ++kf) {
            const float4 mk = *(const float4*)(mask + (size_t)b * S_ + t * 64 + kf * 16 + lg * 4);
#pragma unroll
            for (int r = 0; r < 4; ++r) {
                const float mkr = (r == 0) ? mk.x : (r == 1) ? mk.y : (r == 2) ? mk.z : mk.w;
                p[kf * 4 + r] = sc[kf][r] * 0.125f + mkr;
                tmax = fmaxf(tmax, p[kf * 4 + r]);
            }
        }
        tmax = fmaxf(tmax, __shfl_xor(tmax, 16));
        tmax = fmaxf(tmax, __shfl_xor(tmax, 32));

        const float mnew = fmaxf(m_r, tmax);
        const float scl  = __expf(m_r - mnew);
        m_r = mnew;

        float psum = 0.f;
#pragma unroll
        for (int i = 0; i < 16; ++i) {
            p[i] = __expf(p[i] - mnew);
            psum += p[i];
        }
        psum += __shfl_xor(psum, 16);
        psum += __shfl_xor(psum, 32);
        l_r = l_r * scl + psum;

#pragma unroll
        for (int fd = 0; fd < 4; ++fd)
#pragma unroll
            for (int r = 0; r < 4; ++r) ctx[fd][r] *= scl;

#pragma unroll
        for (int kf = 0; kf < 4; ++kf)
#pragma unroll
            for (int rr = 0; rr < 2; ++rr) {
                ushort2 wv;
                wv.x = f2b(p[kf * 4 + 2 * rr]);
                wv.y = f2b(p[kf * 4 + 2 * rr + 1]);
                *(ushort2*)(Psm + l15 * 128 +
                            (((kf * 16 + lg * 4 + 2 * rr) * 2) ^ xo_p)) = wv;
            }
        asm volatile("s_waitcnt lgkmcnt(0)" ::: "memory");

#pragma unroll
        for (int s = 0; s < 2; ++s) {
            const bf16_8 pf = *(const bf16_8*)(Psm + l15 * 128 +
                                ((s * 64 + lg * 16) ^ xo_p));
            const __attribute__((address_space(3))) char* a3 = vtr + s * 1024;
            u32x2 r0, r1, r2, r3, r4, r5, r6, r7;
            asm volatile(
                "ds_read_b64_tr_b16 %0, %8 offset:0\n\t"
                "ds_read_b64_tr_b16 %1, %8 offset:128\n\t"
                "ds_read_b64_tr_b16 %2, %8 offset:2048\n\t"
                "ds_read_b64_tr_b16 %3, %8 offset:2176\n\t"
                "ds_read_b64_tr_b16 %4, %8 offset:4096\n\t"
                "ds_read_b64_tr_b16 %5, %8 offset:4224\n\t"
                "ds_read_b64_tr_b16 %6, %8 offset:6144\n\t"
                "ds_read_b64_tr_b16 %7, %8 offset:6272\n\t"
                "s_waitcnt lgkmcnt(0)"
                : "=&v"(r0), "=&v"(r1), "=&v"(r2), "=&v"(r3),
                  "=&v"(r4), "=&v"(r5), "=&v"(r6), "=&v"(r7)
                : "v"(a3));
            union Cv { unsigned u[4]; bf16_8 v; };
            Cv c0; c0.u[0] = r0.x; c0.u[1] = r0.y; c0.u[2] = r1.x; c0.u[3] = r1.y;
            Cv c1; c1.u[0] = r2.x; c1.u[1] = r2.y; c1.u[2] = r3.x; c1.u[3] = r3.y;
            Cv c2; c2.u[0] = r4.x; c2.u[1] = r4.y; c2.u[2] = r5.x; c2.u[3] = r5.y;
            Cv c3; c3.u[0] = r6.x; c3.u[1] = r6.y; c3.u[2] = r7.x; c3.u[3] = r7.y;
            ctx[0] = __builtin_amdgcn_mfma_f32_16x16x32_bf16(c0.v, pf, ctx[0], 0, 0, 0);
            ctx[1] = __builtin_amdgcn_mfma_f32_16x16x32_bf16(c1.v, pf, ctx[1], 0, 0, 0);
            ctx[2] = __builtin_amdgcn_mfma_f32_16x16x32_bf16(c2.v, pf, ctx[2], 0, 0, 0);
            ctx[3] = __builtin_amdgcn_mfma_f32_16x16x32_bf16(c3.v, pf, ctx[3], 0, 0, 0);
        }
    }

    const float inv = 1.f / l_r;
    const size_t qrow = outhead + (size_t)(q0 + l15) * D_;
#pragma unroll
    for (int fd = 0; fd < 4; ++fd) {
        ushort4 o;
        o.x = f2b(ctx[fd][0] * inv);
        o.y = f2b(ctx[fd][1] * inv);
        o.z = f2b(ctx[fd][2] * inv);
        o.w = f2b(ctx[fd][3] * inv);
        *(ushort4*)(ctxb + qrow + fd * 16 + lg * 4) = o;
    }
}

// ---------------------------------------------------------------------------
extern "C" void kernel_launch(void* const* d_in, const int* in_sizes, int n_in,
                              void* d_out, int out_size, void* d_ws, size_t ws_size,
                              hipStream_t stream)
{
    const float* h    = (const float*)d_in[0];
    const float* mask = (const float*)d_in[1];
    const float* Wq   = (const float*)d_in[2];
    const float* bq   = (const float*)d_in[3];
    const float* Wk   = (const float*)d_in[4];
    const float* bk   = (const float*)d_in[5];
    const float* Wv   = (const float*)d_in[6];
    const float* bv   = (const float*)d_in[7];
    const float* Wo   = (const float*)d_in[8];
    const float* bo   = (const float*)d_in[9];
    const float* ln1g = (const float*)d_in[10];
    const float* ln1b = (const float*)d_in[11];
    const float* Wi   = (const float*)d_in[12];
    const float* bi   = (const float*)d_in[13];
    const float* Wout = (const float*)d_in[14];
    const float* bout = (const float*)d_in[15];
    const float* ln2g = (const float*)d_in[16];
    const float* ln2b = (const float*)d_in[17];
    float* out = (float*)d_out;

    char* w = (char*)d_ws;
    const size_t MiB = 1ull << 20;
    // liveness-packed layout, peak 104 MiB:
    u16*   Woutt  = (u16*)(w + 0);             // [0,8)   live to FFN2
    u16*   Wit    = (u16*)(w + 8 * MiB);       // [8,16)  live to FFN1
    u16*   hb     = (u16*)(w + 16 * MiB);      // [16,24) dead after QKV
    u16*   woP0   = (u16*)(w + 16 * MiB);      //   then Wo partial 0 (bf16)
    u16*   ffP1   = (u16*)(w + 16 * MiB);      //   then FFN2 partial 1
    u16*   Wqkvt  = (u16*)(w + 24 * MiB);      // [24,30) dead after QKV
    u16*   ffP2   = (u16*)(w + 24 * MiB);      //   then FFN2 partial 2
    u16*   Wot    = (u16*)(w + 30 * MiB);      // [30,32) dead after Wo-splitk
    u16*   QKVb   = (u16*)(w + 32 * MiB);      // [32,56) dead after attn
    u16*   woP1   = (u16*)(w + 32 * MiB);      //   then Wo partial 1
    u16*   ffP3   = (u16*)(w + 32 * MiB);      //   then FFN2 partial 3
    float* attnF  = (float*)(w + 40 * MiB);    // [40,56) live to ln2
    u16*   attnB  = (u16*)(w + 56 * MiB);      // [56,64) dead after FFN1
    u16*   interB = (u16*)(w + 64 * MiB);      // [64,96) dead after FFN2
    u16*   ctxb   = (u16*)(w + 96 * MiB);      // [96,104) dead after Wo-splitk
    u16*   ffP0   = (u16*)(w + 96 * MiB);      //   then FFN2 partial 0

    const dim3 blk(256);
    PB zp; zp.p[0] = zp.p[1] = zp.p[2] = zp.p[3] = nullptr;

    // fused prep: h -> bf16 + 6 weight transposes, one dispatch
    Prep pp;
    pp.s[0] = Wq;   pp.d[0] = Wqkvt;                 pp.K[0] = D_; pp.N[0] = D_;
    pp.s[1] = Wk;   pp.d[1] = Wqkvt + 1024 * 1024;   pp.K[1] = D_; pp.N[1] = D_;
    pp.s[2] = Wv;   pp.d[2] = Wqkvt + 2 * 1024 * 1024; pp.K[2] = D_; pp.N[2] = D_;
    pp.s[3] = Wo;   pp.d[3] = Wot;                   pp.K[3] = D_; pp.N[3] = D_;
    pp.s[4] = Wi;   pp.d[4] = Wit;                   pp.K[4] = D_; pp.N[4] = I_;
    pp.s[5] = Wout; pp.d[5] = Woutt;                 pp.K[5] = I_; pp.N[5] = D_;
    pp.cin  = (const float4*)h;
    pp.cout = (ushort4*)hb;
    prep_all<<<dim3(128, 32, 7), blk, 0, stream>>>(pp);

    // fused QKV projection: 256^2 8-phase, grid (12,16)
    gemm256<0><<<dim3(12, 16, 1), dim3(512), 0, stream>>>(
        hb, Wqkvt, bq, bk, bv, QKVb, zp, 3072, 1024, 1024);

    // attention: 512 blocks x 512 threads, XCD-chunked swizzle
    attn_mfma<<<dim3(512), dim3(512), 0, stream>>>(
        QKVb, QKVb + 1024, QKVb + 2048, mask, ctxb, 3072);

    // Wo projection, split-K x2 -> bf16 partials; reduce+bias+res(h)+LN1
    PB woP; woP.p[0] = woP0; woP.p[1] = woP1; woP.p[2] = nullptr; woP.p[3] = nullptr;
    gemm_splitk<<<dim3(8, 32, 2), blk, 0, stream>>>(ctxb, Wot, woP, D_, D_, 512);
    ln_reduce<2><<<dim3(M_), blk, 0, stream>>>(woP, bo, h, ln1g, ln1b, attnF, attnB);

    // FFN1: erf-GELU GEMM, 256^2 8-phase, grid (16,16)
    gemm256<1><<<dim3(16, 16, 1), dim3(512), 0, stream>>>(
        attnB, Wit, bi, nullptr, nullptr, interB, zp, 4096, 1024, 1024);

    // FFN2: 256^2 8-phase split-K x4 -> bf16 partials; reduce+bias+res+LN2 -> out
    PB ffP; ffP.p[0] = ffP0; ffP.p[1] = ffP1; ffP.p[2] = ffP2; ffP.p[3] = ffP3;
    gemm256<2><<<dim3(4, 16, 4), dim3(512), 0, stream>>>(
        interB, Woutt, nullptr, nullptr, nullptr, nullptr, ffP, 1024, 4096, 4096);
    ln_reduce<4><<<dim3(M_), blk, 0, stream>>>(ffP, bout, attnF, ln2g, ln2b, out, nullptr);
}